// Round 7
// baseline (252.352 us; speedup 1.0000x reference)
//
#include <hip/hip_runtime.h>
#include <hip/hip_fp16.h>
#include <cstdint>

#define V_N 50000
#define E_N 800000
#define NODE_IN 128
#define EDGE_IN 16
#define HF 128
#define NEG_SLOPE 0.2f
#define NB_SCAN 196   // ceil(50000/256)

// ---- workspace layout (4-byte word offsets) ----
#define OFF_FT    0         // V*64 words (f16 ft, 128/node, permuted layout)
#define OFF_EL    3200000   // V*4
#define OFF_ER    3400000   // V*4
#define OFF_DEG   3600000   // V ints
#define OFF_ROW   3650000   // V+1 ints (+pad)
#define OFF_BSUM  3700004   // 256
#define OFF_RANK  3700260   // E ints
#define OFF_REC   4500260   // E*4 words (uint4 records; 16B-aligned)
#define OFF_WATT  7700260   // 64
#define OFF_BFRAG 7700324   // 16384 words (16B-aligned)
// total ~7.72M words = 30.9 MB

typedef short bf16x8 __attribute__((ext_vector_type(8)));
typedef float f32x4 __attribute__((ext_vector_type(4)));

__device__ __forceinline__ unsigned short f2bf(float f) {
    unsigned u = __float_as_uint(f);
    u += 0x7fffu + ((u >> 16) & 1u);   // round-to-nearest-even
    return (unsigned short)(u >> 16);
}
__device__ __forceinline__ unsigned pk2(float lo, float hi) {
    return (unsigned)f2bf(lo) | ((unsigned)f2bf(hi) << 16);
}
__device__ __forceinline__ float bflo(unsigned w) { return __uint_as_float(w << 16); }
__device__ __forceinline__ float bfhi(unsigned w) { return __uint_as_float(w & 0xffff0000u); }

typedef __fp16 fp16x2 __attribute__((ext_vector_type(2)));
__device__ __forceinline__ unsigned pkh2(float a, float b) {
    fp16x2 h = __builtin_amdgcn_cvt_pkrtz(a, b);   // v_cvt_pkrtz_f16_f32
    return __builtin_bit_cast(unsigned, h);
}
__device__ __forceinline__ __half2 u2h(unsigned u) {
    return __builtin_bit_cast(__half2, u);
}
__device__ __forceinline__ unsigned h2u(__half2 h) {
    return __builtin_bit_cast(unsigned, h);
}

// k_prep: zero deg; watt[k][h] = sum_f We[k,h*32+f]*attn_e[h,f]; Bfrag conv.
__global__ void k_prep(const float* __restrict__ We,
                       const float* __restrict__ attn_e,
                       const float* __restrict__ Wn,
                       const float* __restrict__ Wr,
                       float* __restrict__ watt,
                       unsigned* __restrict__ bfrag,
                       int* __restrict__ deg) {
    int g = blockIdx.x * 256 + threadIdx.x;
    for (int i = g; i < V_N; i += 16384) deg[i] = 0;
    if (blockIdx.x == 0 && threadIdx.x < 64) {
        int k = threadIdx.x >> 2, h = threadIdx.x & 3;
        float s = 0.f;
        #pragma unroll
        for (int f = 0; f < 32; f++)
            s += We[k * HF + h * 32 + f] * attn_e[h * 32 + f];
        watt[k * 4 + h] = s;
    }
    if (g < 16384) {
        int c    = g >> 8;
        int lane = (g >> 2) & 63;
        int jp   = g & 3;
        int nt = c >> 2, ks = c & 3;
        int col = nt * 16 + (lane & 15);
        int k   = ks * 32 + (lane >> 4) * 8 + jp * 2;
        const float* W = (col < 128) ? Wn : Wr;
        int cc = col & 127;
        float x0 = W[(size_t)k * 128 + cc];
        float x1 = W[(size_t)(k + 1) * 128 + cc];
        bfrag[g] = pk2(x0, x1);
    }
}

// Node kernel (MFMA): 32 nodes x 256 cols (128 ft | 128 residual) per block.
// D-layout: col=lane&15, row=quad*4+reg. ft stored f16 in permuted layout:
//   ushort idx = node*128 + w*64 + n15*4 + tt  (col = w*64 + tt*16 + n15)
__global__ __launch_bounds__(256) void k_node(
    const float* __restrict__ nf, const unsigned* __restrict__ bfragw,
    const float* __restrict__ attn_l, const float* __restrict__ attn_r,
    const float* __restrict__ bias,
    unsigned short* __restrict__ ftw, float* __restrict__ el,
    float* __restrict__ er, float* __restrict__ out)
{
    __shared__ __align__(16) float sSf[32 * 140];
    unsigned short* sA = (unsigned short*)sSf;      // stride 136 bf16/row

    const int t = threadIdx.x;
    const int lane = t & 63;
    const int w = t >> 6;
    const int nb = blockIdx.x * 32;
    const int n15 = lane & 15;
    const int q = lane >> 4;
    const unsigned short* bfrag = (const unsigned short*)bfragw;

    #pragma unroll
    for (int i = 0; i < 4; i++) {
        int f = t + i * 256;
        int node = f >> 5;
        int kc = (f & 31) * 4;
        float4 v = {0.f, 0.f, 0.f, 0.f};
        if (nb + node < V_N)
            v = *(const float4*)(nf + (size_t)(nb + node) * NODE_IN + kc);
        uint2 u2 = make_uint2(pk2(v.x, v.y), pk2(v.z, v.w));
        *(uint2*)&sA[node * 136 + kc] = u2;
    }
    __syncthreads();

    f32x4 acc[2][4];
    #pragma unroll
    for (int m = 0; m < 2; m++)
        #pragma unroll
        for (int tt = 0; tt < 4; tt++) acc[m][tt] = (f32x4){0.f, 0.f, 0.f, 0.f};

    #pragma unroll
    for (int ks = 0; ks < 4; ks++) {
        bf16x8 a0 = *(const bf16x8*)&sA[n15 * 136 + ks * 32 + q * 8];
        bf16x8 a1 = *(const bf16x8*)&sA[(16 + n15) * 136 + ks * 32 + q * 8];
        #pragma unroll
        for (int tt = 0; tt < 4; tt++) {
            int nt = w * 4 + tt;
            bf16x8 b = *(const bf16x8*)(bfrag + ((size_t)(nt * 4 + ks) * 64 + lane) * 8);
            acc[0][tt] = __builtin_amdgcn_mfma_f32_16x16x32_bf16(a0, b, acc[0][tt], 0, 0, 0);
            acc[1][tt] = __builtin_amdgcn_mfma_f32_16x16x32_bf16(a1, b, acc[1][tt], 0, 0, 0);
        }
    }

    if (w < 2) {
        // el/er per-head dots from fragments
        #pragma unroll
        for (int hh = 0; hh < 2; hh++) {
            int head = w * 2 + hh;
            float al0 = attn_l[head * 32 + n15];
            float al1 = attn_l[head * 32 + 16 + n15];
            float ar0 = attn_r[head * 32 + n15];
            float ar1 = attn_r[head * 32 + 16 + n15];
            #pragma unroll
            for (int m = 0; m < 2; m++) {
                #pragma unroll
                for (int r = 0; r < 4; r++) {
                    float fa = acc[m][hh * 2][r], fb = acc[m][hh * 2 + 1][r];
                    float elp = fa * al0 + fb * al1;
                    float erp = fa * ar0 + fb * ar1;
                    elp += __shfl_xor(elp, 1); erp += __shfl_xor(erp, 1);
                    elp += __shfl_xor(elp, 2); erp += __shfl_xor(erp, 2);
                    elp += __shfl_xor(elp, 4); erp += __shfl_xor(erp, 4);
                    elp += __shfl_xor(elp, 8); erp += __shfl_xor(erp, 8);
                    int node = nb + m * 16 + q * 4 + r;
                    if (n15 == 0 && node < V_N) {
                        el[node * 4 + head] = elp;
                        er[node * 4 + head] = erp;
                    }
                }
            }
        }
        // ft f16 direct store from fragments (coalesced 8B per lane)
        #pragma unroll
        for (int m = 0; m < 2; m++)
            #pragma unroll
            for (int r = 0; r < 4; r++) {
                int node = nb + m * 16 + q * 4 + r;
                if (node < V_N) {
                    uint2 u;
                    u.x = pkh2(acc[m][0][r], acc[m][1][r]);
                    u.y = pkh2(acc[m][2][r], acc[m][3][r]);
                    *(uint2*)(ftw + (size_t)node * 128 + w * 64 + n15 * 4) = u;
                }
            }
    }
    __syncthreads();

    // residual: waves 2,3 stage fp32 -> LDS, then coalesced out = res + bias
    if (w >= 2) {
        #pragma unroll
        for (int m = 0; m < 2; m++)
            #pragma unroll
            for (int tt = 0; tt < 4; tt++)
                #pragma unroll
                for (int r = 0; r < 4; r++)
                    sSf[(m * 16 + q * 4 + r) * 140 + (w - 2) * 64 + tt * 16 + n15] =
                        acc[m][tt][r];
    }
    __syncthreads();
    #pragma unroll
    for (int i = 0; i < 4; i++) {
        int u = t + i * 256;
        int node = u >> 5, c4 = (u & 31) * 4;
        if (nb + node < V_N) {
            float4 v = *(float4*)&sSf[node * 140 + c4];
            float4 b4 = *(const float4*)(bias + c4);
            v.x += b4.x; v.y += b4.y; v.z += b4.z; v.w += b4.w;
            *(float4*)(out + (size_t)(nb + node) * HF + c4) = v;
        }
    }
}

// ---- CSR build: hist + rank in one pass ----
__global__ void k_hist(const int* __restrict__ dst, int* __restrict__ deg,
                       int* __restrict__ rank) {
    int e = blockIdx.x * 256 + threadIdx.x;
    if (e < E_N) rank[e] = atomicAdd(&deg[dst[e]], 1);
}

__global__ __launch_bounds__(256) void k_scan1(const int* __restrict__ deg,
                                               int* __restrict__ rowp,
                                               int* __restrict__ bsum) {
    __shared__ int sh[256];
    int t = threadIdx.x, b = blockIdx.x;
    int i = b * 256 + t;
    int v = (i < V_N) ? deg[i] : 0;
    sh[t] = v;
    __syncthreads();
    #pragma unroll
    for (int off = 1; off < 256; off <<= 1) {
        int u = (t >= off) ? sh[t - off] : 0;
        __syncthreads();
        sh[t] += u;
        __syncthreads();
    }
    if (i < V_N) rowp[i] = sh[t] - v;          // exclusive within block
    if (t == 255) bsum[b] = sh[255];
}

__global__ __launch_bounds__(256) void k_scan23(int* __restrict__ rowp,
                                                const int* __restrict__ bsum) {
    __shared__ int sh[256];
    int t = threadIdx.x, b = blockIdx.x;
    int v = (t < NB_SCAN) ? bsum[t] : 0;
    sh[t] = v;
    __syncthreads();
    #pragma unroll
    for (int off = 1; off < 256; off <<= 1) {
        int u = (t >= off) ? sh[t - off] : 0;
        __syncthreads();
        sh[t] += u;
        __syncthreads();
    }
    int boff = (b == 0) ? 0 : sh[b - 1];
    int i = b * 256 + t;
    if (i < V_N) rowp[i] += boff;
    if (i == 0) rowp[V_N] = E_N;
}

// Streaming + edge softmax numerator: ex = exp(leaky(el[src]+er[dst]+ee)).
// record[p] = {src, ex01(bf16), ex23(bf16), 0}, p = rowp[dst] + rank[e].
// No max-subtraction: logits are O(1) (weights ~0.05), exp is safe and
// exp(x)/sum exp(x) is mathematically identical to the max-shifted form.
__global__ __launch_bounds__(256) void k_escatter(
    const float* __restrict__ ef, const int* __restrict__ src,
    const int* __restrict__ dst, const int* __restrict__ rank,
    const int* __restrict__ rowp, const float* __restrict__ watt,
    const float* __restrict__ el, const float* __restrict__ er,
    uint4* __restrict__ rec)
{
    __shared__ float sw[64];
    if (threadIdx.x < 64) sw[threadIdx.x] = watt[threadIdx.x];
    __syncthreads();
    int e = blockIdx.x * 256 + threadIdx.x;
    if (e >= E_N) return;

    float eev[4] = {0.f, 0.f, 0.f, 0.f};
    #pragma unroll
    for (int kq = 0; kq < 4; kq++) {
        float4 v = *(const float4*)(ef + (size_t)e * EDGE_IN + kq * 4);
        float vv[4] = {v.x, v.y, v.z, v.w};
        #pragma unroll
        for (int j = 0; j < 4; j++) {
            int k = kq * 4 + j;
            #pragma unroll
            for (int h = 0; h < 4; h++) eev[h] += vv[j] * sw[k * 4 + h];
        }
    }
    int s = src[e], d = dst[e];
    float4 el4 = *(const float4*)(el + (size_t)s * 4);
    float4 er4 = *(const float4*)(er + (size_t)d * 4);
    float x0 = el4.x + er4.x + eev[0];
    float x1 = el4.y + er4.y + eev[1];
    float x2 = el4.z + er4.z + eev[2];
    float x3 = el4.w + er4.w + eev[3];
    x0 = x0 >= 0.f ? x0 : NEG_SLOPE * x0;
    x1 = x1 >= 0.f ? x1 : NEG_SLOPE * x1;
    x2 = x2 >= 0.f ? x2 : NEG_SLOPE * x2;
    x3 = x3 >= 0.f ? x3 : NEG_SLOPE * x3;
    int p = rowp[d] + rank[e];
    uint4 r;
    r.x = (unsigned)s;
    r.y = pk2(__expf(x0), __expf(x1));
    r.z = pk2(__expf(x2), __expf(x3));
    r.w = 0;
    rec[p] = r;
}

// One wave per dst. Records carry ex directly -> no logit math here.
// 8 edges per inner iteration (2 per quarter-wave, 2 loads in flight),
// lane li owns 16B (8 f16) of the permuted ftw row; v_pk_fma_f16 accum.
__global__ __launch_bounds__(256) void k_gather(
    const int* __restrict__ row, const uint4* __restrict__ rec,
    const unsigned short* __restrict__ ftw, float* __restrict__ out)
{
    __shared__ unsigned aw[4][64][4];    // per edge: 4 dup-half2 (one per head)
    const int lane = threadIdx.x & 63;
    const int wid  = threadIdx.x >> 6;
    const int d = blockIdx.x * 4 + wid;
    if (d >= V_N) return;
    const int n0 = row[d];
    const int deg = row[d + 1] - n0;
    if (deg == 0) return;

    // phase A: sum ex; stash first chunk in regs
    int   si0 = 0;
    float4 ex0 = {0.f, 0.f, 0.f, 0.f};
    float4 s4  = {0.f, 0.f, 0.f, 0.f};
    for (int i = lane; i < deg; i += 64) {
        uint4 r = rec[n0 + i];
        float4 ex = {bflo(r.y), bfhi(r.y), bflo(r.z), bfhi(r.z)};
        if (i == lane) { si0 = (int)r.x; ex0 = ex; }
        s4.x += ex.x; s4.y += ex.y; s4.z += ex.z; s4.w += ex.w;
    }
    #pragma unroll
    for (int off = 1; off < 64; off <<= 1) {
        s4.x += __shfl_xor(s4.x, off);
        s4.y += __shfl_xor(s4.y, off);
        s4.z += __shfl_xor(s4.z, off);
        s4.w += __shfl_xor(s4.w, off);
    }
    float4 rs4 = {1.f / s4.x, 1.f / s4.y, 1.f / s4.z, 1.f / s4.w};

    const int qw = lane >> 4, li = lane & 15;
    const int wsel = li >> 3;            // which 64-col half
    __half2 ha0 = u2h(0u), ha1 = u2h(0u), ha2 = u2h(0u), ha3 = u2h(0u);
    __half2 hb0 = u2h(0u), hb1 = u2h(0u), hb2 = u2h(0u), hb3 = u2h(0u);

    for (int i0 = 0; i0 < deg; i0 += 64) {
        int chunk = min(64, deg - i0);
        int si = 0;
        float4 a4 = {0.f, 0.f, 0.f, 0.f};
        if (lane < chunk) {
            if (i0 == 0) {
                si = si0;
                a4.x = ex0.x * rs4.x; a4.y = ex0.y * rs4.y;
                a4.z = ex0.z * rs4.z; a4.w = ex0.w * rs4.w;
            } else {
                uint4 r = rec[n0 + i0 + lane];
                si = (int)r.x;
                a4.x = bflo(r.y) * rs4.x; a4.y = bfhi(r.y) * rs4.y;
                a4.z = bflo(r.z) * rs4.z; a4.w = bfhi(r.z) * rs4.w;
            }
        }
        uint4 ap;
        ap.x = pkh2(a4.x, a4.x); ap.y = pkh2(a4.y, a4.y);
        ap.z = pkh2(a4.z, a4.z); ap.w = pkh2(a4.w, a4.w);
        *(uint4*)&aw[wid][lane][0] = ap;
        asm volatile("s_waitcnt lgkmcnt(0)" ::: "memory");

        int iters = (chunk + 7) & ~7;
        for (int j = 0; j < iters; j += 8) {
            int jq0 = j + qw, jq1 = j + qw + 4;
            int sidx0 = __shfl(si, jq0);        // jq>=chunk -> si=0, a=0
            int sidx1 = __shfl(si, jq1);
            uint2 au0 = *(const uint2*)&aw[wid][jq0][wsel * 2];
            uint2 au1 = *(const uint2*)&aw[wid][jq1][wsel * 2];
            uint4 wv0 = *(const uint4*)(ftw + (size_t)sidx0 * 128 + li * 8);
            uint4 wv1 = *(const uint4*)(ftw + (size_t)sidx1 * 128 + li * 8);
            ha0 = __hfma2(u2h(wv0.x), u2h(au0.x), ha0);
            ha1 = __hfma2(u2h(wv0.y), u2h(au0.y), ha1);
            ha2 = __hfma2(u2h(wv0.z), u2h(au0.x), ha2);
            ha3 = __hfma2(u2h(wv0.w), u2h(au0.y), ha3);
            hb0 = __hfma2(u2h(wv1.x), u2h(au1.x), hb0);
            hb1 = __hfma2(u2h(wv1.y), u2h(au1.y), hb1);
            hb2 = __hfma2(u2h(wv1.z), u2h(au1.x), hb2);
            hb3 = __hfma2(u2h(wv1.w), u2h(au1.y), hb3);
        }
    }
    ha0 = __hadd2(ha0, hb0); ha1 = __hadd2(ha1, hb1);
    ha2 = __hadd2(ha2, hb2); ha3 = __hadd2(ha3, hb3);
    ha0 = __hadd2(ha0, u2h(__shfl_xor(h2u(ha0), 16)));
    ha1 = __hadd2(ha1, u2h(__shfl_xor(h2u(ha1), 16)));
    ha2 = __hadd2(ha2, u2h(__shfl_xor(h2u(ha2), 16)));
    ha3 = __hadd2(ha3, u2h(__shfl_xor(h2u(ha3), 16)));
    ha0 = __hadd2(ha0, u2h(__shfl_xor(h2u(ha0), 32)));
    ha1 = __hadd2(ha1, u2h(__shfl_xor(h2u(ha1), 32)));
    ha2 = __hadd2(ha2, u2h(__shfl_xor(h2u(ha2), 32)));
    ha3 = __hadd2(ha3, u2h(__shfl_xor(h2u(ha3), 32)));
    if (qw == 0) {
        // lane li holds cols {wsel*64 + tt*16 + 2*(li&7) + s}, s=0,1
        float* op = out + (size_t)d * HF + wsel * 64 + (li & 7) * 2;
        float2 r;
        r = *(float2*)(op +  0); r.x += __low2float(ha0);  r.y += __low2float(ha2);  *(float2*)(op +  0) = r;
        r = *(float2*)(op + 16); r.x += __high2float(ha0); r.y += __high2float(ha2); *(float2*)(op + 16) = r;
        r = *(float2*)(op + 32); r.x += __low2float(ha1);  r.y += __low2float(ha3);  *(float2*)(op + 32) = r;
        r = *(float2*)(op + 48); r.x += __high2float(ha1); r.y += __high2float(ha3); *(float2*)(op + 48) = r;
    }
}

extern "C" void kernel_launch(void* const* d_in, const int* in_sizes, int n_in,
                              void* d_out, int out_size, void* d_ws, size_t ws_size,
                              hipStream_t stream) {
    const float* nf     = (const float*)d_in[0];
    const float* ef     = (const float*)d_in[1];
    const int*   src    = (const int*)d_in[2];
    const int*   dst    = (const int*)d_in[3];
    const float* Wn     = (const float*)d_in[4];
    const float* We     = (const float*)d_in[5];
    const float* attn_l = (const float*)d_in[6];
    const float* attn_r = (const float*)d_in[7];
    const float* attn_e = (const float*)d_in[8];
    const float* Wr     = (const float*)d_in[9];
    const float* bias   = (const float*)d_in[10];
    float* out = (float*)d_out;

    unsigned* wsw  = (unsigned*)d_ws;
    unsigned short* ftw = (unsigned short*)(wsw + OFF_FT);
    float* el      = (float*)(wsw + OFF_EL);
    float* er      = (float*)(wsw + OFF_ER);
    int* deg       = (int*)(wsw + OFF_DEG);
    int* rowp      = (int*)(wsw + OFF_ROW);
    int* bsum      = (int*)(wsw + OFF_BSUM);
    int* rank      = (int*)(wsw + OFF_RANK);
    uint4* rec     = (uint4*)(wsw + OFF_REC);
    float* watt    = (float*)(wsw + OFF_WATT);
    unsigned* bfrag = wsw + OFF_BFRAG;

    k_prep<<<64, 256, 0, stream>>>(We, attn_e, Wn, Wr, watt, bfrag, deg);
    k_hist<<<(E_N + 255) / 256, 256, 0, stream>>>(dst, deg, rank);
    k_scan1<<<NB_SCAN, 256, 0, stream>>>(deg, rowp, bsum);
    k_scan23<<<NB_SCAN, 256, 0, stream>>>(rowp, bsum);
    k_node<<<(V_N + 31) / 32, 256, 0, stream>>>(nf, bfrag, attn_l, attn_r,
                                                bias, ftw, el, er, out);
    k_escatter<<<(E_N + 255) / 256, 256, 0, stream>>>(ef, src, dst, rank,
                                                      rowp, watt, el, er, rec);
    k_gather<<<(V_N + 3) / 4, 256, 0, stream>>>(rowp, rec, ftw, out);
}

// Round 8
// 249.242 us; speedup vs baseline: 1.0125x; 1.0125x over previous
//
#include <hip/hip_runtime.h>
#include <hip/hip_fp16.h>
#include <cstdint>

#define V_N 50000
#define E_N 800000
#define NODE_IN 128
#define EDGE_IN 16
#define HF 128
#define NEG_SLOPE 0.2f
#define NB_SCAN 196   // ceil(50000/256)

// ---- workspace layout (4-byte word offsets) ----
#define OFF_FT    0         // V*64 words (f16 ft, 128/node, permuted layout)
#define OFF_EL    3200000   // V*4
#define OFF_ER    3400000   // V*4
#define OFF_DEG   3600000   // V ints
#define OFF_ROW   3650000   // V+1 ints (+pad)
#define OFF_BSUM  3700004   // 256
#define OFF_RANK  3700260   // E ints
#define OFF_REC   4500260   // E*4 words (uint4 records; 16B-aligned)
#define OFF_WATT  7700260   // 64
#define OFF_BFRAG 7700324   // 16384 words (16B-aligned)
// total ~7.72M words = 30.9 MB

typedef short bf16x8 __attribute__((ext_vector_type(8)));
typedef float f32x4 __attribute__((ext_vector_type(4)));

__device__ __forceinline__ unsigned short f2bf(float f) {
    unsigned u = __float_as_uint(f);
    u += 0x7fffu + ((u >> 16) & 1u);   // round-to-nearest-even
    return (unsigned short)(u >> 16);
}
__device__ __forceinline__ unsigned pk2(float lo, float hi) {
    return (unsigned)f2bf(lo) | ((unsigned)f2bf(hi) << 16);
}
__device__ __forceinline__ float bflo(unsigned w) { return __uint_as_float(w << 16); }
__device__ __forceinline__ float bfhi(unsigned w) { return __uint_as_float(w & 0xffff0000u); }

typedef __fp16 fp16x2 __attribute__((ext_vector_type(2)));
__device__ __forceinline__ unsigned pkh2(float a, float b) {
    fp16x2 h = __builtin_amdgcn_cvt_pkrtz(a, b);   // v_cvt_pkrtz_f16_f32
    return __builtin_bit_cast(unsigned, h);
}
__device__ __forceinline__ __half2 u2h(unsigned u) {
    return __builtin_bit_cast(__half2, u);
}
__device__ __forceinline__ unsigned h2u(__half2 h) {
    return __builtin_bit_cast(unsigned, h);
}

// k_prep: zero deg; watt[k][h] = sum_f We[k,h*32+f]*attn_e[h,f]; Bfrag conv.
__global__ void k_prep(const float* __restrict__ We,
                       const float* __restrict__ attn_e,
                       const float* __restrict__ Wn,
                       const float* __restrict__ Wr,
                       float* __restrict__ watt,
                       unsigned* __restrict__ bfrag,
                       int* __restrict__ deg) {
    int g = blockIdx.x * 256 + threadIdx.x;
    for (int i = g; i < V_N; i += 16384) deg[i] = 0;
    if (blockIdx.x == 0 && threadIdx.x < 64) {
        int k = threadIdx.x >> 2, h = threadIdx.x & 3;
        float s = 0.f;
        #pragma unroll
        for (int f = 0; f < 32; f++)
            s += We[k * HF + h * 32 + f] * attn_e[h * 32 + f];
        watt[k * 4 + h] = s;
    }
    if (g < 16384) {
        int c    = g >> 8;
        int lane = (g >> 2) & 63;
        int jp   = g & 3;
        int nt = c >> 2, ks = c & 3;
        int col = nt * 16 + (lane & 15);
        int k   = ks * 32 + (lane >> 4) * 8 + jp * 2;
        const float* W = (col < 128) ? Wn : Wr;
        int cc = col & 127;
        float x0 = W[(size_t)k * 128 + cc];
        float x1 = W[(size_t)(k + 1) * 128 + cc];
        bfrag[g] = pk2(x0, x1);
    }
}

// Node kernel (MFMA): 32 nodes x 256 cols (128 ft | 128 residual) per block.
// D-layout: col=lane&15, row=quad*4+reg. ft stored f16 in permuted layout:
//   ushort idx = node*128 + w*64 + n15*4 + tt  (col = w*64 + tt*16 + n15)
__global__ __launch_bounds__(256) void k_node(
    const float* __restrict__ nf, const unsigned* __restrict__ bfragw,
    const float* __restrict__ attn_l, const float* __restrict__ attn_r,
    const float* __restrict__ bias,
    unsigned short* __restrict__ ftw, float* __restrict__ el,
    float* __restrict__ er, float* __restrict__ out)
{
    __shared__ __align__(16) float sSf[32 * 140];
    unsigned short* sA = (unsigned short*)sSf;      // stride 136 bf16/row

    const int t = threadIdx.x;
    const int lane = t & 63;
    const int w = t >> 6;
    const int nb = blockIdx.x * 32;
    const int n15 = lane & 15;
    const int q = lane >> 4;
    const unsigned short* bfrag = (const unsigned short*)bfragw;

    #pragma unroll
    for (int i = 0; i < 4; i++) {
        int f = t + i * 256;
        int node = f >> 5;
        int kc = (f & 31) * 4;
        float4 v = {0.f, 0.f, 0.f, 0.f};
        if (nb + node < V_N)
            v = *(const float4*)(nf + (size_t)(nb + node) * NODE_IN + kc);
        uint2 u2 = make_uint2(pk2(v.x, v.y), pk2(v.z, v.w));
        *(uint2*)&sA[node * 136 + kc] = u2;
    }
    __syncthreads();

    f32x4 acc[2][4];
    #pragma unroll
    for (int m = 0; m < 2; m++)
        #pragma unroll
        for (int tt = 0; tt < 4; tt++) acc[m][tt] = (f32x4){0.f, 0.f, 0.f, 0.f};

    #pragma unroll
    for (int ks = 0; ks < 4; ks++) {
        bf16x8 a0 = *(const bf16x8*)&sA[n15 * 136 + ks * 32 + q * 8];
        bf16x8 a1 = *(const bf16x8*)&sA[(16 + n15) * 136 + ks * 32 + q * 8];
        #pragma unroll
        for (int tt = 0; tt < 4; tt++) {
            int nt = w * 4 + tt;
            bf16x8 b = *(const bf16x8*)(bfrag + ((size_t)(nt * 4 + ks) * 64 + lane) * 8);
            acc[0][tt] = __builtin_amdgcn_mfma_f32_16x16x32_bf16(a0, b, acc[0][tt], 0, 0, 0);
            acc[1][tt] = __builtin_amdgcn_mfma_f32_16x16x32_bf16(a1, b, acc[1][tt], 0, 0, 0);
        }
    }

    if (w < 2) {
        // el/er per-head dots from fragments
        #pragma unroll
        for (int hh = 0; hh < 2; hh++) {
            int head = w * 2 + hh;
            float al0 = attn_l[head * 32 + n15];
            float al1 = attn_l[head * 32 + 16 + n15];
            float ar0 = attn_r[head * 32 + n15];
            float ar1 = attn_r[head * 32 + 16 + n15];
            #pragma unroll
            for (int m = 0; m < 2; m++) {
                #pragma unroll
                for (int r = 0; r < 4; r++) {
                    float fa = acc[m][hh * 2][r], fb = acc[m][hh * 2 + 1][r];
                    float elp = fa * al0 + fb * al1;
                    float erp = fa * ar0 + fb * ar1;
                    elp += __shfl_xor(elp, 1); erp += __shfl_xor(erp, 1);
                    elp += __shfl_xor(elp, 2); erp += __shfl_xor(erp, 2);
                    elp += __shfl_xor(elp, 4); erp += __shfl_xor(erp, 4);
                    elp += __shfl_xor(elp, 8); erp += __shfl_xor(erp, 8);
                    int node = nb + m * 16 + q * 4 + r;
                    if (n15 == 0 && node < V_N) {
                        el[node * 4 + head] = elp;
                        er[node * 4 + head] = erp;
                    }
                }
            }
        }
        // ft f16 direct store from fragments (coalesced 8B per lane)
        #pragma unroll
        for (int m = 0; m < 2; m++)
            #pragma unroll
            for (int r = 0; r < 4; r++) {
                int node = nb + m * 16 + q * 4 + r;
                if (node < V_N) {
                    uint2 u;
                    u.x = pkh2(acc[m][0][r], acc[m][1][r]);
                    u.y = pkh2(acc[m][2][r], acc[m][3][r]);
                    *(uint2*)(ftw + (size_t)node * 128 + w * 64 + n15 * 4) = u;
                }
            }
    }
    __syncthreads();

    // residual: waves 2,3 stage fp32 -> LDS, then coalesced out = res + bias
    if (w >= 2) {
        #pragma unroll
        for (int m = 0; m < 2; m++)
            #pragma unroll
            for (int tt = 0; tt < 4; tt++)
                #pragma unroll
                for (int r = 0; r < 4; r++)
                    sSf[(m * 16 + q * 4 + r) * 140 + (w - 2) * 64 + tt * 16 + n15] =
                        acc[m][tt][r];
    }
    __syncthreads();
    #pragma unroll
    for (int i = 0; i < 4; i++) {
        int u = t + i * 256;
        int node = u >> 5, c4 = (u & 31) * 4;
        if (nb + node < V_N) {
            float4 v = *(float4*)&sSf[node * 140 + c4];
            float4 b4 = *(const float4*)(bias + c4);
            v.x += b4.x; v.y += b4.y; v.z += b4.z; v.w += b4.w;
            *(float4*)(out + (size_t)(nb + node) * HF + c4) = v;
        }
    }
}

// ---- CSR build: hist + rank, 2 edges/thread for MLP ----
__global__ void k_hist(const int* __restrict__ dst, int* __restrict__ deg,
                       int* __restrict__ rank) {
    int e0 = blockIdx.x * 512 + threadIdx.x;
    #pragma unroll
    for (int u = 0; u < 2; u++) {
        int e = e0 + u * 256;
        if (e < E_N) rank[e] = atomicAdd(&deg[dst[e]], 1);
    }
}

__global__ __launch_bounds__(256) void k_scan1(const int* __restrict__ deg,
                                               int* __restrict__ rowp,
                                               int* __restrict__ bsum) {
    __shared__ int sh[256];
    int t = threadIdx.x, b = blockIdx.x;
    int i = b * 256 + t;
    int v = (i < V_N) ? deg[i] : 0;
    sh[t] = v;
    __syncthreads();
    #pragma unroll
    for (int off = 1; off < 256; off <<= 1) {
        int u = (t >= off) ? sh[t - off] : 0;
        __syncthreads();
        sh[t] += u;
        __syncthreads();
    }
    if (i < V_N) rowp[i] = sh[t] - v;          // exclusive within block
    if (t == 255) bsum[b] = sh[255];
}

__global__ __launch_bounds__(256) void k_scan23(int* __restrict__ rowp,
                                                const int* __restrict__ bsum) {
    __shared__ int sh[256];
    int t = threadIdx.x, b = blockIdx.x;
    int v = (t < NB_SCAN) ? bsum[t] : 0;
    sh[t] = v;
    __syncthreads();
    #pragma unroll
    for (int off = 1; off < 256; off <<= 1) {
        int u = (t >= off) ? sh[t - off] : 0;
        __syncthreads();
        sh[t] += u;
        __syncthreads();
    }
    int boff = (b == 0) ? 0 : sh[b - 1];
    int i = b * 256 + t;
    if (i < V_N) rowp[i] += boff;
    if (i == 0) rowp[V_N] = E_N;
}

// Streaming, 2 edges/thread: record[p] = {src, lee01, lee23, 0} where
// lee = el[src] + ee (bf16). er/leaky/exp applied in gather (er is
// wave-uniform there). Only random ops: el gather + record store.
__global__ __launch_bounds__(256) void k_escatter(
    const float* __restrict__ ef, const int* __restrict__ src,
    const int* __restrict__ dst, const int* __restrict__ rank,
    const int* __restrict__ rowp, const float* __restrict__ watt,
    const float* __restrict__ el, uint4* __restrict__ rec)
{
    __shared__ float sw[64];
    if (threadIdx.x < 64) sw[threadIdx.x] = watt[threadIdx.x];
    __syncthreads();
    const int e0 = blockIdx.x * 512 + threadIdx.x;

    int   sv[2], pv[2];
    bool  ok[2];
    float eev[2][4];
    #pragma unroll
    for (int u = 0; u < 2; u++) {
        int e = e0 + u * 256;
        ok[u] = e < E_N;
        int ec = ok[u] ? e : 0;
        sv[u] = src[ec];
        pv[u] = rowp[dst[ec]] + rank[ec];
        #pragma unroll
        for (int h = 0; h < 4; h++) eev[u][h] = 0.f;
        #pragma unroll
        for (int kq = 0; kq < 4; kq++) {
            float4 v = *(const float4*)(ef + (size_t)ec * EDGE_IN + kq * 4);
            float vv[4] = {v.x, v.y, v.z, v.w};
            #pragma unroll
            for (int j = 0; j < 4; j++) {
                int k = kq * 4 + j;
                #pragma unroll
                for (int h = 0; h < 4; h++) eev[u][h] += vv[j] * sw[k * 4 + h];
            }
        }
    }
    #pragma unroll
    for (int u = 0; u < 2; u++) {
        float4 el4 = *(const float4*)(el + (size_t)sv[u] * 4);
        uint4 r;
        r.x = (unsigned)sv[u];
        r.y = pk2(el4.x + eev[u][0], el4.y + eev[u][1]);
        r.z = pk2(el4.z + eev[u][2], el4.w + eev[u][3]);
        r.w = 0;
        if (ok[u]) rec[pv[u]] = r;
    }
}

// One wave per dst. Records carry lee; er[d] is wave-uniform; leaky+exp here.
// 8 edges per inner iteration (2 per quarter-wave, 2 loads in flight),
// lane li owns 16B (8 f16) of the permuted ftw row; v_pk_fma_f16 accum.
__global__ __launch_bounds__(256) void k_gather(
    const int* __restrict__ row, const uint4* __restrict__ rec,
    const float* __restrict__ er,
    const unsigned short* __restrict__ ftw, float* __restrict__ out)
{
    __shared__ unsigned aw[4][64][4];    // per edge: 4 dup-half2 (one per head)
    const int lane = threadIdx.x & 63;
    const int wid  = threadIdx.x >> 6;
    const int d = blockIdx.x * 4 + wid;
    if (d >= V_N) return;
    const int n0 = row[d];
    const int deg = row[d + 1] - n0;
    if (deg == 0) return;

    const float4 er4 = *(const float4*)(er + (size_t)d * 4);

    // phase A: ex = exp(leaky(lee+er)); wave sums; stash first chunk in regs
    int   si0 = 0;
    float4 ex0 = {0.f, 0.f, 0.f, 0.f};
    float4 s4  = {0.f, 0.f, 0.f, 0.f};
    for (int i = lane; i < deg; i += 64) {
        uint4 r = rec[n0 + i];
        float x0 = bflo(r.y) + er4.x;
        float x1 = bfhi(r.y) + er4.y;
        float x2 = bflo(r.z) + er4.z;
        float x3 = bfhi(r.z) + er4.w;
        x0 = x0 >= 0.f ? x0 : NEG_SLOPE * x0;
        x1 = x1 >= 0.f ? x1 : NEG_SLOPE * x1;
        x2 = x2 >= 0.f ? x2 : NEG_SLOPE * x2;
        x3 = x3 >= 0.f ? x3 : NEG_SLOPE * x3;
        float4 ex = {__expf(x0), __expf(x1), __expf(x2), __expf(x3)};
        if (i == lane) { si0 = (int)r.x; ex0 = ex; }
        s4.x += ex.x; s4.y += ex.y; s4.z += ex.z; s4.w += ex.w;
    }
    #pragma unroll
    for (int off = 1; off < 64; off <<= 1) {
        s4.x += __shfl_xor(s4.x, off);
        s4.y += __shfl_xor(s4.y, off);
        s4.z += __shfl_xor(s4.z, off);
        s4.w += __shfl_xor(s4.w, off);
    }
    float4 rs4 = {1.f / s4.x, 1.f / s4.y, 1.f / s4.z, 1.f / s4.w};

    const int qw = lane >> 4, li = lane & 15;
    const int wsel = li >> 3;            // which 64-col half
    __half2 ha0 = u2h(0u), ha1 = u2h(0u), ha2 = u2h(0u), ha3 = u2h(0u);
    __half2 hb0 = u2h(0u), hb1 = u2h(0u), hb2 = u2h(0u), hb3 = u2h(0u);

    for (int i0 = 0; i0 < deg; i0 += 64) {
        int chunk = min(64, deg - i0);
        int si = 0;
        float4 a4 = {0.f, 0.f, 0.f, 0.f};
        if (lane < chunk) {
            if (i0 == 0) {
                si = si0;
                a4.x = ex0.x * rs4.x; a4.y = ex0.y * rs4.y;
                a4.z = ex0.z * rs4.z; a4.w = ex0.w * rs4.w;
            } else {
                uint4 r = rec[n0 + i0 + lane];
                si = (int)r.x;
                float x0 = bflo(r.y) + er4.x;
                float x1 = bfhi(r.y) + er4.y;
                float x2 = bflo(r.z) + er4.z;
                float x3 = bfhi(r.z) + er4.w;
                x0 = x0 >= 0.f ? x0 : NEG_SLOPE * x0;
                x1 = x1 >= 0.f ? x1 : NEG_SLOPE * x1;
                x2 = x2 >= 0.f ? x2 : NEG_SLOPE * x2;
                x3 = x3 >= 0.f ? x3 : NEG_SLOPE * x3;
                a4.x = __expf(x0) * rs4.x; a4.y = __expf(x1) * rs4.y;
                a4.z = __expf(x2) * rs4.z; a4.w = __expf(x3) * rs4.w;
            }
        }
        uint4 ap;
        ap.x = pkh2(a4.x, a4.x); ap.y = pkh2(a4.y, a4.y);
        ap.z = pkh2(a4.z, a4.z); ap.w = pkh2(a4.w, a4.w);
        *(uint4*)&aw[wid][lane][0] = ap;
        asm volatile("s_waitcnt lgkmcnt(0)" ::: "memory");

        int iters = (chunk + 7) & ~7;
        for (int j = 0; j < iters; j += 8) {
            int jq0 = j + qw, jq1 = j + qw + 4;
            int sidx0 = __shfl(si, jq0);        // jq>=chunk -> si=0, a=0
            int sidx1 = __shfl(si, jq1);
            uint2 au0 = *(const uint2*)&aw[wid][jq0][wsel * 2];
            uint2 au1 = *(const uint2*)&aw[wid][jq1][wsel * 2];
            uint4 wv0 = *(const uint4*)(ftw + (size_t)sidx0 * 128 + li * 8);
            uint4 wv1 = *(const uint4*)(ftw + (size_t)sidx1 * 128 + li * 8);
            ha0 = __hfma2(u2h(wv0.x), u2h(au0.x), ha0);
            ha1 = __hfma2(u2h(wv0.y), u2h(au0.y), ha1);
            ha2 = __hfma2(u2h(wv0.z), u2h(au0.x), ha2);
            ha3 = __hfma2(u2h(wv0.w), u2h(au0.y), ha3);
            hb0 = __hfma2(u2h(wv1.x), u2h(au1.x), hb0);
            hb1 = __hfma2(u2h(wv1.y), u2h(au1.y), hb1);
            hb2 = __hfma2(u2h(wv1.z), u2h(au1.x), hb2);
            hb3 = __hfma2(u2h(wv1.w), u2h(au1.y), hb3);
        }
    }
    ha0 = __hadd2(ha0, hb0); ha1 = __hadd2(ha1, hb1);
    ha2 = __hadd2(ha2, hb2); ha3 = __hadd2(ha3, hb3);
    ha0 = __hadd2(ha0, u2h(__shfl_xor(h2u(ha0), 16)));
    ha1 = __hadd2(ha1, u2h(__shfl_xor(h2u(ha1), 16)));
    ha2 = __hadd2(ha2, u2h(__shfl_xor(h2u(ha2), 16)));
    ha3 = __hadd2(ha3, u2h(__shfl_xor(h2u(ha3), 16)));
    ha0 = __hadd2(ha0, u2h(__shfl_xor(h2u(ha0), 32)));
    ha1 = __hadd2(ha1, u2h(__shfl_xor(h2u(ha1), 32)));
    ha2 = __hadd2(ha2, u2h(__shfl_xor(h2u(ha2), 32)));
    ha3 = __hadd2(ha3, u2h(__shfl_xor(h2u(ha3), 32)));
    if (qw == 0) {
        // lane li holds cols {wsel*64 + tt*16 + 2*(li&7) + s}, s=0,1
        float* op = out + (size_t)d * HF + wsel * 64 + (li & 7) * 2;
        float2 r;
        r = *(float2*)(op +  0); r.x += __low2float(ha0);  r.y += __low2float(ha2);  *(float2*)(op +  0) = r;
        r = *(float2*)(op + 16); r.x += __high2float(ha0); r.y += __high2float(ha2); *(float2*)(op + 16) = r;
        r = *(float2*)(op + 32); r.x += __low2float(ha1);  r.y += __low2float(ha3);  *(float2*)(op + 32) = r;
        r = *(float2*)(op + 48); r.x += __high2float(ha1); r.y += __high2float(ha3); *(float2*)(op + 48) = r;
    }
}

extern "C" void kernel_launch(void* const* d_in, const int* in_sizes, int n_in,
                              void* d_out, int out_size, void* d_ws, size_t ws_size,
                              hipStream_t stream) {
    const float* nf     = (const float*)d_in[0];
    const float* ef     = (const float*)d_in[1];
    const int*   src    = (const int*)d_in[2];
    const int*   dst    = (const int*)d_in[3];
    const float* Wn     = (const float*)d_in[4];
    const float* We     = (const float*)d_in[5];
    const float* attn_l = (const float*)d_in[6];
    const float* attn_r = (const float*)d_in[7];
    const float* attn_e = (const float*)d_in[8];
    const float* Wr     = (const float*)d_in[9];
    const float* bias   = (const float*)d_in[10];
    float* out = (float*)d_out;

    unsigned* wsw  = (unsigned*)d_ws;
    unsigned short* ftw = (unsigned short*)(wsw + OFF_FT);
    float* el      = (float*)(wsw + OFF_EL);
    float* er      = (float*)(wsw + OFF_ER);
    int* deg       = (int*)(wsw + OFF_DEG);
    int* rowp      = (int*)(wsw + OFF_ROW);
    int* bsum      = (int*)(wsw + OFF_BSUM);
    int* rank      = (int*)(wsw + OFF_RANK);
    uint4* rec     = (uint4*)(wsw + OFF_REC);
    float* watt    = (float*)(wsw + OFF_WATT);
    unsigned* bfrag = wsw + OFF_BFRAG;

    k_prep<<<64, 256, 0, stream>>>(We, attn_e, Wn, Wr, watt, bfrag, deg);
    k_hist<<<(E_N + 511) / 512, 256, 0, stream>>>(dst, deg, rank);
    k_scan1<<<NB_SCAN, 256, 0, stream>>>(deg, rowp, bsum);
    k_scan23<<<NB_SCAN, 256, 0, stream>>>(rowp, bsum);
    k_node<<<(V_N + 31) / 32, 256, 0, stream>>>(nf, bfrag, attn_l, attn_r,
                                                bias, ftw, el, er, out);
    k_escatter<<<(E_N + 511) / 512, 256, 0, stream>>>(ef, src, dst, rank,
                                                      rowp, watt, el, rec);
    k_gather<<<(V_N + 3) / 4, 256, 0, stream>>>(rowp, rec, er, ftw, out);
}

// Round 9
// 245.114 us; speedup vs baseline: 1.0295x; 1.0168x over previous
//
#include <hip/hip_runtime.h>
#include <hip/hip_fp16.h>
#include <cstdint>

#define V_N 50000
#define E_N 800000
#define NODE_IN 128
#define EDGE_IN 16
#define HF 128
#define NEG_SLOPE 0.2f
#define NB_SCAN 196   // ceil(50000/256)

// ---- workspace layout (4-byte word offsets) ----
#define OFF_FT    0         // V*64 words (f16 ft, 128/node, head-major layout)
#define OFF_EL    3200000   // V*4
#define OFF_ER    3400000   // V*4
#define OFF_DEG   3600000   // V ints
#define OFF_ROW   3650000   // V+1 ints (+pad)
#define OFF_BSUM  3700004   // 256
#define OFF_RANK  3700260   // E ints
#define OFF_REC   4500260   // E*4 words (uint4 records; 16B-aligned)
#define OFF_WATT  7700260   // 64
#define OFF_BFRAG 7700324   // 16384 words (16B-aligned)
// total ~7.72M words = 30.9 MB

typedef short bf16x8 __attribute__((ext_vector_type(8)));
typedef float f32x4 __attribute__((ext_vector_type(4)));

__device__ __forceinline__ unsigned short f2bf(float f) {
    unsigned u = __float_as_uint(f);
    u += 0x7fffu + ((u >> 16) & 1u);   // round-to-nearest-even
    return (unsigned short)(u >> 16);
}
__device__ __forceinline__ unsigned pk2(float lo, float hi) {
    return (unsigned)f2bf(lo) | ((unsigned)f2bf(hi) << 16);
}
__device__ __forceinline__ float bflo(unsigned w) { return __uint_as_float(w << 16); }
__device__ __forceinline__ float bfhi(unsigned w) { return __uint_as_float(w & 0xffff0000u); }

typedef __fp16 fp16x2 __attribute__((ext_vector_type(2)));
__device__ __forceinline__ unsigned pkh2(float a, float b) {
    fp16x2 h = __builtin_amdgcn_cvt_pkrtz(a, b);   // v_cvt_pkrtz_f16_f32
    return __builtin_bit_cast(unsigned, h);
}
__device__ __forceinline__ __half2 u2h(unsigned u) {
    return __builtin_bit_cast(__half2, u);
}
__device__ __forceinline__ unsigned h2u(__half2 h) {
    return __builtin_bit_cast(unsigned, h);
}

// k_prep: zero deg; watt[k][h] = sum_f We[k,h*32+f]*attn_e[h,f]; Bfrag conv.
__global__ void k_prep(const float* __restrict__ We,
                       const float* __restrict__ attn_e,
                       const float* __restrict__ Wn,
                       const float* __restrict__ Wr,
                       float* __restrict__ watt,
                       unsigned* __restrict__ bfrag,
                       int* __restrict__ deg) {
    int g = blockIdx.x * 256 + threadIdx.x;
    for (int i = g; i < V_N; i += 16384) deg[i] = 0;
    if (blockIdx.x == 0 && threadIdx.x < 64) {
        int k = threadIdx.x >> 2, h = threadIdx.x & 3;
        float s = 0.f;
        #pragma unroll
        for (int f = 0; f < 32; f++)
            s += We[k * HF + h * 32 + f] * attn_e[h * 32 + f];
        watt[k * 4 + h] = s;
    }
    if (g < 16384) {
        int c    = g >> 8;
        int lane = (g >> 2) & 63;
        int jp   = g & 3;
        int nt = c >> 2, ks = c & 3;
        int col = nt * 16 + (lane & 15);
        int k   = ks * 32 + (lane >> 4) * 8 + jp * 2;
        const float* W = (col < 128) ? Wn : Wr;
        int cc = col & 127;
        float x0 = W[(size_t)k * 128 + cc];
        float x1 = W[(size_t)(k + 1) * 128 + cc];
        bfrag[g] = pk2(x0, x1);
    }
}

// Node kernel (MFMA): 32 nodes x 256 cols per block; wave w == head w.
// Wave w owns nt tiles {2w, 2w+1} (ft cols of head w) and {8+2w, 9+2w}
// (residual cols 32w..32w+31) -> el/er/ft/residual work balanced 4-way.
// ftw layout (head-major): ushort idx = node*128 + head*32 + n15*2 + tt,
// i.e. col = head*32 + tt*16 + n15.
__global__ __launch_bounds__(256) void k_node(
    const float* __restrict__ nf, const unsigned* __restrict__ bfragw,
    const float* __restrict__ attn_l, const float* __restrict__ attn_r,
    const float* __restrict__ bias,
    unsigned* __restrict__ ftw, float* __restrict__ el,
    float* __restrict__ er, float* __restrict__ out)
{
    __shared__ __align__(16) float sSf[32 * 140];
    unsigned short* sA = (unsigned short*)sSf;      // stride 136 bf16/row

    const int t = threadIdx.x;
    const int lane = t & 63;
    const int w = t >> 6;                            // == head
    const int nb = blockIdx.x * 32;
    const int n15 = lane & 15;
    const int q = lane >> 4;
    const unsigned short* bfrag = (const unsigned short*)bfragw;

    #pragma unroll
    for (int i = 0; i < 4; i++) {
        int f = t + i * 256;
        int node = f >> 5;
        int kc = (f & 31) * 4;
        float4 v = {0.f, 0.f, 0.f, 0.f};
        if (nb + node < V_N)
            v = *(const float4*)(nf + (size_t)(nb + node) * NODE_IN + kc);
        uint2 u2 = make_uint2(pk2(v.x, v.y), pk2(v.z, v.w));
        *(uint2*)&sA[node * 136 + kc] = u2;
    }
    __syncthreads();

    f32x4 acc[2][4];
    #pragma unroll
    for (int m = 0; m < 2; m++)
        #pragma unroll
        for (int tt = 0; tt < 4; tt++) acc[m][tt] = (f32x4){0.f, 0.f, 0.f, 0.f};

    #pragma unroll
    for (int ks = 0; ks < 4; ks++) {
        bf16x8 a0 = *(const bf16x8*)&sA[n15 * 136 + ks * 32 + q * 8];
        bf16x8 a1 = *(const bf16x8*)&sA[(16 + n15) * 136 + ks * 32 + q * 8];
        #pragma unroll
        for (int tt = 0; tt < 4; tt++) {
            int nt = (tt < 2) ? (2 * w + tt) : (8 + 2 * w + (tt - 2));
            bf16x8 b = *(const bf16x8*)(bfrag + ((size_t)(nt * 4 + ks) * 64 + lane) * 8);
            acc[0][tt] = __builtin_amdgcn_mfma_f32_16x16x32_bf16(a0, b, acc[0][tt], 0, 0, 0);
            acc[1][tt] = __builtin_amdgcn_mfma_f32_16x16x32_bf16(a1, b, acc[1][tt], 0, 0, 0);
        }
    }

    // el/er for head w (all waves busy)
    {
        float al0 = attn_l[w * 32 + n15];
        float al1 = attn_l[w * 32 + 16 + n15];
        float ar0 = attn_r[w * 32 + n15];
        float ar1 = attn_r[w * 32 + 16 + n15];
        #pragma unroll
        for (int m = 0; m < 2; m++) {
            #pragma unroll
            for (int r = 0; r < 4; r++) {
                float fa = acc[m][0][r], fb = acc[m][1][r];
                float elp = fa * al0 + fb * al1;
                float erp = fa * ar0 + fb * ar1;
                elp += __shfl_xor(elp, 1); erp += __shfl_xor(erp, 1);
                elp += __shfl_xor(elp, 2); erp += __shfl_xor(erp, 2);
                elp += __shfl_xor(elp, 4); erp += __shfl_xor(erp, 4);
                elp += __shfl_xor(elp, 8); erp += __shfl_xor(erp, 8);
                int node = nb + m * 16 + q * 4 + r;
                if (n15 == 0 && node < V_N) {
                    el[node * 4 + w] = elp;
                    er[node * 4 + w] = erp;
                }
            }
        }
    }
    // ft f16 store, head-major: uint idx = node*64 + w*16 + n15
    #pragma unroll
    for (int m = 0; m < 2; m++)
        #pragma unroll
        for (int r = 0; r < 4; r++) {
            int node = nb + m * 16 + q * 4 + r;
            if (node < V_N)
                ftw[(size_t)node * 64 + w * 16 + n15] =
                    pkh2(acc[m][0][r], acc[m][1][r]);
        }
    __syncthreads();

    // residual: wave w stages cols 32w..32w+31 (tt=2,3)
    #pragma unroll
    for (int m = 0; m < 2; m++)
        #pragma unroll
        for (int tt = 2; tt < 4; tt++)
            #pragma unroll
            for (int r = 0; r < 4; r++)
                sSf[(m * 16 + q * 4 + r) * 140 + w * 32 + (tt - 2) * 16 + n15] =
                    acc[m][tt][r];
    __syncthreads();
    #pragma unroll
    for (int i = 0; i < 4; i++) {
        int u = t + i * 256;
        int node = u >> 5, c4 = (u & 31) * 4;
        if (nb + node < V_N) {
            float4 v = *(float4*)&sSf[node * 140 + c4];
            float4 b4 = *(const float4*)(bias + c4);
            v.x += b4.x; v.y += b4.y; v.z += b4.z; v.w += b4.w;
            *(float4*)(out + (size_t)(nb + node) * HF + c4) = v;
        }
    }
}

// ---- CSR build: hist + rank ----
__global__ void k_hist(const int* __restrict__ dst, int* __restrict__ deg,
                       int* __restrict__ rank) {
    int e = blockIdx.x * 256 + threadIdx.x;
    if (e < E_N) rank[e] = atomicAdd(&deg[dst[e]], 1);
}

__global__ __launch_bounds__(256) void k_scan1(const int* __restrict__ deg,
                                               int* __restrict__ rowp,
                                               int* __restrict__ bsum) {
    __shared__ int sh[256];
    int t = threadIdx.x, b = blockIdx.x;
    int i = b * 256 + t;
    int v = (i < V_N) ? deg[i] : 0;
    sh[t] = v;
    __syncthreads();
    #pragma unroll
    for (int off = 1; off < 256; off <<= 1) {
        int u = (t >= off) ? sh[t - off] : 0;
        __syncthreads();
        sh[t] += u;
        __syncthreads();
    }
    if (i < V_N) rowp[i] = sh[t] - v;          // exclusive within block
    if (t == 255) bsum[b] = sh[255];
}

__global__ __launch_bounds__(256) void k_scan23(int* __restrict__ rowp,
                                                const int* __restrict__ bsum) {
    __shared__ int sh[256];
    int t = threadIdx.x, b = blockIdx.x;
    int v = (t < NB_SCAN) ? bsum[t] : 0;
    sh[t] = v;
    __syncthreads();
    #pragma unroll
    for (int off = 1; off < 256; off <<= 1) {
        int u = (t >= off) ? sh[t - off] : 0;
        __syncthreads();
        sh[t] += u;
        __syncthreads();
    }
    int boff = (b == 0) ? 0 : sh[b - 1];
    int i = b * 256 + t;
    if (i < V_N) rowp[i] += boff;
    if (i == 0) rowp[V_N] = E_N;
}

// Streaming escatter, fully-coalesced ef reads (quad of lanes per edge),
// then 1 edge/thread scatter: record[p] = {src, lee01, lee23, 0} where
// lee = el[src] + ee (bf16). 800000 == 3125*256 exactly -> no guards.
__global__ __launch_bounds__(256) void k_escatter(
    const float* __restrict__ ef, const int* __restrict__ src,
    const int* __restrict__ dst, const int* __restrict__ rank,
    const int* __restrict__ rowp, const float* __restrict__ watt,
    const float* __restrict__ el, uint4* __restrict__ rec)
{
    __shared__ float sw[64];
    __shared__ __align__(16) float see[256][4];
    const int t = threadIdx.x;
    if (t < 64) sw[t] = watt[t];
    __syncthreads();
    const int base = blockIdx.x * 256;
    const int lane = t & 63, w = t >> 6;
    const int k0 = (lane & 3) * 4;

    // phase 1: quad (4 lanes) per edge; lane reads 16B of the 64B ef row
    #pragma unroll
    for (int r = 0; r < 4; r++) {
        int le = w * 64 + r * 16 + (lane >> 2);     // local edge 0..255
        float4 v = *(const float4*)(ef + (size_t)(base + le) * EDGE_IN + k0);
        float e0 = 0.f, e1 = 0.f, e2 = 0.f, e3 = 0.f;
        float vv[4] = {v.x, v.y, v.z, v.w};
        #pragma unroll
        for (int j = 0; j < 4; j++) {
            int k = k0 + j;
            e0 += vv[j] * sw[k * 4 + 0];
            e1 += vv[j] * sw[k * 4 + 1];
            e2 += vv[j] * sw[k * 4 + 2];
            e3 += vv[j] * sw[k * 4 + 3];
        }
        e0 += __shfl_xor(e0, 1); e1 += __shfl_xor(e1, 1);
        e2 += __shfl_xor(e2, 1); e3 += __shfl_xor(e3, 1);
        e0 += __shfl_xor(e0, 2); e1 += __shfl_xor(e1, 2);
        e2 += __shfl_xor(e2, 2); e3 += __shfl_xor(e3, 2);
        if ((lane & 3) == 0) {
            float4 o = {e0, e1, e2, e3};
            *(float4*)&see[le][0] = o;
        }
    }
    __syncthreads();

    // phase 2: 1 edge/thread
    int e = base + t;
    int s = src[e], d = dst[e];
    int p = rowp[d] + rank[e];
    float4 ee = *(float4*)&see[t][0];
    float4 el4 = *(const float4*)(el + (size_t)s * 4);
    uint4 rr;
    rr.x = (unsigned)s;
    rr.y = pk2(el4.x + ee.x, el4.y + ee.y);
    rr.z = pk2(el4.z + ee.z, el4.w + ee.w);
    rr.w = 0;
    rec[p] = rr;
}

// One wave per dst, SINGLE PASS: accumulate U = sum ex*ft (f16) and
// s = sum ex simultaneously; normalize at the end (no max-shift needed,
// exp(x)/sum exp(x) identical). 8 edges per inner iteration.
// ftw head-major: lane li's uint4 (8 f16) all belong to head li>>2.
__global__ __launch_bounds__(256) void k_gather(
    const int* __restrict__ row, const uint4* __restrict__ rec,
    const float* __restrict__ er,
    const unsigned* __restrict__ ftw, float* __restrict__ out)
{
    __shared__ unsigned aw[4][64][4];    // per edge: dup-half2 ex per head
    const int lane = threadIdx.x & 63;
    const int wid  = threadIdx.x >> 6;
    const int d = blockIdx.x * 4 + wid;
    if (d >= V_N) return;
    const int n0 = row[d];
    const int deg = row[d + 1] - n0;
    if (deg == 0) return;

    const float4 er4 = *(const float4*)(er + (size_t)d * 4);

    const int qw = lane >> 4, li = lane & 15;
    const int head = li >> 2;
    float4 s4 = {0.f, 0.f, 0.f, 0.f};
    __half2 ha0 = u2h(0u), ha1 = u2h(0u), ha2 = u2h(0u), ha3 = u2h(0u);
    __half2 hb0 = u2h(0u), hb1 = u2h(0u), hb2 = u2h(0u), hb3 = u2h(0u);

    for (int i0 = 0; i0 < deg; i0 += 64) {
        int chunk = min(64, deg - i0);
        int si = 0;
        float4 ex = {0.f, 0.f, 0.f, 0.f};
        if (lane < chunk) {
            uint4 r = rec[n0 + i0 + lane];
            si = (int)r.x;
            float x0 = bflo(r.y) + er4.x;
            float x1 = bfhi(r.y) + er4.y;
            float x2 = bflo(r.z) + er4.z;
            float x3 = bfhi(r.z) + er4.w;
            x0 = x0 >= 0.f ? x0 : NEG_SLOPE * x0;
            x1 = x1 >= 0.f ? x1 : NEG_SLOPE * x1;
            x2 = x2 >= 0.f ? x2 : NEG_SLOPE * x2;
            x3 = x3 >= 0.f ? x3 : NEG_SLOPE * x3;
            ex.x = __expf(x0); ex.y = __expf(x1);
            ex.z = __expf(x2); ex.w = __expf(x3);
            s4.x += ex.x; s4.y += ex.y; s4.z += ex.z; s4.w += ex.w;
        }
        uint4 ap;
        ap.x = pkh2(ex.x, ex.x); ap.y = pkh2(ex.y, ex.y);
        ap.z = pkh2(ex.z, ex.z); ap.w = pkh2(ex.w, ex.w);
        *(uint4*)&aw[wid][lane][0] = ap;
        asm volatile("s_waitcnt lgkmcnt(0)" ::: "memory");

        int iters = (chunk + 7) & ~7;
        for (int j = 0; j < iters; j += 8) {
            int jq0 = j + qw, jq1 = j + qw + 4;
            int sidx0 = __shfl(si, jq0);        // jq>=chunk -> si=0, ex=0
            int sidx1 = __shfl(si, jq1);
            unsigned au0 = aw[wid][jq0][head];
            unsigned au1 = aw[wid][jq1][head];
            uint4 wv0 = *(const uint4*)(ftw + (size_t)sidx0 * 64 + li * 4);
            uint4 wv1 = *(const uint4*)(ftw + (size_t)sidx1 * 64 + li * 4);
            ha0 = __hfma2(u2h(wv0.x), u2h(au0), ha0);
            ha1 = __hfma2(u2h(wv0.y), u2h(au0), ha1);
            ha2 = __hfma2(u2h(wv0.z), u2h(au0), ha2);
            ha3 = __hfma2(u2h(wv0.w), u2h(au0), ha3);
            hb0 = __hfma2(u2h(wv1.x), u2h(au1), hb0);
            hb1 = __hfma2(u2h(wv1.y), u2h(au1), hb1);
            hb2 = __hfma2(u2h(wv1.z), u2h(au1), hb2);
            hb3 = __hfma2(u2h(wv1.w), u2h(au1), hb3);
        }
    }
    // reduce s over wave
    #pragma unroll
    for (int off = 1; off < 64; off <<= 1) {
        s4.x += __shfl_xor(s4.x, off);
        s4.y += __shfl_xor(s4.y, off);
        s4.z += __shfl_xor(s4.z, off);
        s4.w += __shfl_xor(s4.w, off);
    }
    // reduce U over quarter-waves
    ha0 = __hadd2(ha0, hb0); ha1 = __hadd2(ha1, hb1);
    ha2 = __hadd2(ha2, hb2); ha3 = __hadd2(ha3, hb3);
    ha0 = __hadd2(ha0, u2h(__shfl_xor(h2u(ha0), 16)));
    ha1 = __hadd2(ha1, u2h(__shfl_xor(h2u(ha1), 16)));
    ha2 = __hadd2(ha2, u2h(__shfl_xor(h2u(ha2), 16)));
    ha3 = __hadd2(ha3, u2h(__shfl_xor(h2u(ha3), 16)));
    ha0 = __hadd2(ha0, u2h(__shfl_xor(h2u(ha0), 32)));
    ha1 = __hadd2(ha1, u2h(__shfl_xor(h2u(ha1), 32)));
    ha2 = __hadd2(ha2, u2h(__shfl_xor(h2u(ha2), 32)));
    ha3 = __hadd2(ha3, u2h(__shfl_xor(h2u(ha3), 32)));
    if (qw == 0) {
        float rsv = 1.f / (head == 0 ? s4.x : head == 1 ? s4.y :
                           head == 2 ? s4.z : s4.w);
        // lane li: cols head*32 + (li&3)*4 + {0..3} and +16
        float* op = out + (size_t)d * HF + head * 32 + (li & 3) * 4;
        float4 r0 = *(float4*)op;
        r0.x += __low2float(ha0) * rsv; r0.y += __low2float(ha1) * rsv;
        r0.z += __low2float(ha2) * rsv; r0.w += __low2float(ha3) * rsv;
        *(float4*)op = r0;
        float4 r1 = *(float4*)(op + 16);
        r1.x += __high2float(ha0) * rsv; r1.y += __high2float(ha1) * rsv;
        r1.z += __high2float(ha2) * rsv; r1.w += __high2float(ha3) * rsv;
        *(float4*)(op + 16) = r1;
    }
}

extern "C" void kernel_launch(void* const* d_in, const int* in_sizes, int n_in,
                              void* d_out, int out_size, void* d_ws, size_t ws_size,
                              hipStream_t stream) {
    const float* nf     = (const float*)d_in[0];
    const float* ef     = (const float*)d_in[1];
    const int*   src    = (const int*)d_in[2];
    const int*   dst    = (const int*)d_in[3];
    const float* Wn     = (const float*)d_in[4];
    const float* We     = (const float*)d_in[5];
    const float* attn_l = (const float*)d_in[6];
    const float* attn_r = (const float*)d_in[7];
    const float* attn_e = (const float*)d_in[8];
    const float* Wr     = (const float*)d_in[9];
    const float* bias   = (const float*)d_in[10];
    float* out = (float*)d_out;

    unsigned* wsw  = (unsigned*)d_ws;
    unsigned* ftw  = wsw + OFF_FT;
    float* el      = (float*)(wsw + OFF_EL);
    float* er      = (float*)(wsw + OFF_ER);
    int* deg       = (int*)(wsw + OFF_DEG);
    int* rowp      = (int*)(wsw + OFF_ROW);
    int* bsum      = (int*)(wsw + OFF_BSUM);
    int* rank      = (int*)(wsw + OFF_RANK);
    uint4* rec     = (uint4*)(wsw + OFF_REC);
    float* watt    = (float*)(wsw + OFF_WATT);
    unsigned* bfrag = wsw + OFF_BFRAG;

    k_prep<<<64, 256, 0, stream>>>(We, attn_e, Wn, Wr, watt, bfrag, deg);
    k_hist<<<(E_N + 255) / 256, 256, 0, stream>>>(dst, deg, rank);
    k_scan1<<<NB_SCAN, 256, 0, stream>>>(deg, rowp, bsum);
    k_scan23<<<NB_SCAN, 256, 0, stream>>>(rowp, bsum);
    k_node<<<(V_N + 31) / 32, 256, 0, stream>>>(nf, bfrag, attn_l, attn_r,
                                                bias, ftw, el, er, out);
    k_escatter<<<E_N / 256, 256, 0, stream>>>(ef, src, dst, rank,
                                              rowp, watt, el, rec);
    k_gather<<<(V_N + 3) / 4, 256, 0, stream>>>(rowp, rec, er, ftw, out);
}